// Round 10
// baseline (829.203 us; speedup 1.0000x reference)
//
#include <hip/hip_runtime.h>
#include <cmath>

using f16x8  = __attribute__((ext_vector_type(8))) _Float16;
using f32x16 = __attribute__((ext_vector_type(16))) float;

// ========= Layouts =========
// A-blob (x split into f16 hi+lo; slot-major; global->reg):
//   addr(kt, slot, m) = ((kt*8 + slot)*Mc + m)*16 bytes, slot = 2*q + isLo,
//   q = k-octet within kt (k_real = kt*32 + q*8 + e). 1-kt pad (33 kts).
// W-blob (single f16, k-major per 64-u slice; global->reg, coalesced):
//   slice = ((g*4 + nt)*4 + wn); within slice: addr(qg, u) = (qg*64 + u)*16,
//   qg = global k-octet 0..127 (k = qg*8 + e), u = 0..63 within the slice.
//   q dimension padded to 132 (prefetch K+2 reads qg up to 131).

#define WSLICE_STRIDE (132 * 64 * 16)   // 135168 B

// ---------- convert x -> A blob (f16 hi/lo split) ----------
__global__ __launch_bounds__(256)
void bru_conv_a(const float* __restrict__ x, char* __restrict__ Ablob,
                int T, int D, int Tc, int t0, int Mc)
{
    const int idx = blockIdx.x * 256 + threadIdx.x;   // Mc*32 threads
    const int kt = idx / Mc;
    const int m  = idx - kt * Mc;

    const long xrow = (long)(m / Tc) * T + t0 + (m % Tc);
    const float* src = x + xrow * (long)D + kt * 32;

    float v[32];
    #pragma unroll
    for (int i = 0; i < 8; ++i)
        *(float4*)&v[i * 4] = *(const float4*)(src + i * 4);

    #pragma unroll
    for (int q = 0; q < 4; ++q) {
        _Float16 hi[8], lo[8];
        #pragma unroll
        for (int j = 0; j < 8; ++j) {
            float f = v[q * 8 + j];
            hi[j] = (_Float16)f;
            lo[j] = (_Float16)(f - (float)hi[j]);
        }
        char* b0 = Ablob + ((size_t)(kt * 8 + 2 * q) * Mc + m) * 16;
        char* b1 = Ablob + ((size_t)(kt * 8 + 2 * q + 1) * Mc + m) * 16;
        *(f16x8*)b0 = *(f16x8*)hi;
        *(f16x8*)b1 = *(f16x8*)lo;
    }
}

// ---------- convert W (3 gates) -> k-major slice blobs ----------
__global__ __launch_bounds__(256)
void bru_conv_w(const float* __restrict__ wz, const float* __restrict__ wr,
                const float* __restrict__ wh, char* __restrict__ Wblob,
                int D, int U)
{
    const int gid   = blockIdx.x * 256 + threadIdx.x;  // 48*8192 threads
    const int slice = gid >> 13;          // 8192 granules per slice
    const int idx   = gid & 8191;
    const int qg    = idx >> 6;           // 0..127
    const int u     = idx & 63;

    const int g    = slice >> 4;          // slice = (g*4+nt)*4 + wn
    const int rest = slice & 15;
    const int nt   = rest >> 2;
    const int sl   = rest & 3;

    const float* W = (g == 0) ? wz : (g == 1) ? wr : wh;
    const int ucol = nt * 256 + sl * 64 + u;
    const int d0   = qg * 8;

    _Float16 o[8];
    #pragma unroll
    for (int j = 0; j < 8; ++j)
        o[j] = (_Float16)W[(long)(d0 + j) * U + ucol];

    *(f16x8*)(Wblob + (size_t)slice * WSLICE_STRIDE + ((size_t)qg * 64 + u) * 16)
        = *(f16x8*)o;
}

// ---------- f16 2-product MFMA GEMM: no LDS, no barriers ----------
// Block tile 256x256, 8 waves as 2x4 (wave tile 128m x 64n).
// All operands global->register: A double-set (parity), W double-set (parity),
// both staggered one KSTEP ahead. Each wave fully independent.
__global__ __launch_bounds__(512, 2)
void bru_gemm_mfma(const char* __restrict__ Ablob, const char* __restrict__ Wblob,
                   const float* __restrict__ bz, const float* __restrict__ br,
                   const float* __restrict__ bh,
                   _Float16* __restrict__ proj,
                   int nmt, int U, int Mc)
{
    const int ngrid = gridDim.x;
    const int bid   = blockIdx.x;
    int lid = bid;
    if ((ngrid & 7) == 0) lid = (bid & 7) * (ngrid >> 3) + (bid >> 3);
    const int mt  = lid / 12;
    const int rem = lid - mt * 12;
    const int g   = rem >> 2;
    const int nt  = rem & 3;

    const int tid  = threadIdx.x;
    const int lane = tid & 63;
    const int w    = tid >> 6;
    const int wm   = w >> 2, wn = w & 3;   // 2x4 wave grid
    const int l31  = lane & 31;
    const int lhi  = lane >> 5;

    const char* wsrc = Wblob + (size_t)((g * 4 + nt) * 4 + wn) * WSLICE_STRIDE;
    const int arow = mt * 256 + wm * 128 + l31;
    const size_t aMc = (size_t)Mc;

// A half-set for KSTEP K: kt = K>>1, q-slot pair = (K&1)*2 + lhi
#define AADDR(K_, i_, lo_) \
    (Ablob + (((size_t)(((K_) >> 1) * 8 + (((K_) & 1) * 2 + lhi) * 2 + (lo_))) * aMc \
              + (size_t)(arow + (i_) * 32)) * 16)
// W frag for KSTEP K: qg = 2K + lhi
#define WADDR(K_, j_) \
    (wsrc + ((size_t)((2 * (K_) + lhi) * 64 + (j_) * 32 + l31)) * 16)

#define LOADA(AS, K_) \
    _Pragma("unroll") for (int i_ = 0; i_ < 4; ++i_) \
    _Pragma("unroll") for (int lo_ = 0; lo_ < 2; ++lo_) \
        AS[i_][lo_] = *(const f16x8*)AADDR(K_, i_, lo_);

#define LOADW(WS, K_) \
    _Pragma("unroll") for (int j_ = 0; j_ < 2; ++j_) \
        WS[j_] = *(const f16x8*)WADDR(K_, j_);

// 16 MFMA: hi pass (8 independent accs) then lo pass
#define KSTEP(WS, AS) do { \
    __builtin_amdgcn_s_setprio(1); \
    _Pragma("unroll") for (int j_ = 0; j_ < 2; ++j_) \
    _Pragma("unroll") for (int i_ = 0; i_ < 4; ++i_) \
        acc[i_][j_] = __builtin_amdgcn_mfma_f32_32x32x16_f16(AS[i_][0], WS[j_], acc[i_][j_], 0, 0, 0); \
    _Pragma("unroll") for (int j_ = 0; j_ < 2; ++j_) \
    _Pragma("unroll") for (int i_ = 0; i_ < 4; ++i_) \
        acc[i_][j_] = __builtin_amdgcn_mfma_f32_32x32x16_f16(AS[i_][1], WS[j_], acc[i_][j_], 0, 0, 0); \
    __builtin_amdgcn_s_setprio(0); } while (0)

    f32x16 acc[4][2];
    #pragma unroll
    for (int i = 0; i < 4; ++i)
        #pragma unroll
        for (int j = 0; j < 2; ++j) acc[i][j] = (f32x16)0.f;

    f16x8 Ae[4][2], Ao[4][2];   // A sets, even/odd KSTEP parity
    f16x8 We[2], Wo[2];         // W sets, even/odd KSTEP parity

    // prologue: preload KSTEP 0 and 1
    LOADW(We, 0); LOADW(Wo, 1);
    LOADA(Ae, 0); LOADA(Ao, 1);

    // 64 KSTEPs total (K = 4p + c); loads for K+2 issue right after KSTEP K.
    // Pads: A kt up to 32 (33 alloc'd), W qg up to 131 (132 alloc'd).
    for (int p = 0; p < 16; ++p) {
        const int K = 4 * p;
        KSTEP(We, Ae); LOADW(We, K + 2); LOADA(Ae, K + 2);
        KSTEP(Wo, Ao); LOADW(Wo, K + 3); LOADA(Ao, K + 3);
        KSTEP(We, Ae); LOADW(We, K + 4); LOADA(Ae, K + 4);
        KSTEP(Wo, Ao); LOADW(Wo, K + 5); LOADA(Ao, K + 5);
    }
#undef AADDR
#undef WADDR
#undef LOADA
#undef LOADW
#undef KSTEP

    // epilogue: C map (m74/m101): col=lane&31, row=(reg&3)+8*(reg>>2)+4*(lane>>5)
    const float* bias = (g == 0) ? bz : (g == 1) ? br : bh;
    const int n0 = nt * 256 + wn * 64;
    float bcol[2];
    #pragma unroll
    for (int j = 0; j < 2; ++j) bcol[j] = bias[n0 + j * 32 + l31];

    _Float16* cbase = proj + (size_t)g * Mc * U + (size_t)n0 + l31;
    #pragma unroll
    for (int i = 0; i < 4; ++i) {
        #pragma unroll
        for (int j = 0; j < 2; ++j) {
            #pragma unroll
            for (int reg = 0; reg < 16; ++reg) {
                const int row = mt * 256 + wm * 128 + i * 32
                              + (reg & 3) + 8 * (reg >> 2) + 4 * lhi;
                cbase[(size_t)row * U + j * 32] = (_Float16)(acc[i][j][reg] + bcol[j]);
            }
        }
    }
}

// ---------- scan: one thread per (b,u); 8-deep rotating register prefetch ----------
#define PF 8
__global__ __launch_bounds__(256)
void bru_scan(const _Float16* __restrict__ proj,
              const float* __restrict__ mz, const float* __restrict__ mr,
              float* __restrict__ out,
              float* __restrict__ hstate,
              int B, int T, int U, int Tc, int t0, int Mc)
{
    const int idx = blockIdx.x * blockDim.x + threadIdx.x;
    const int b = idx / U;
    const int u = idx - b * U;

    float h = (t0 == 0) ? 0.f : hstate[idx];
    const float vmz = mz[u];
    const float vmr = mr[u];

    const _Float16* pz = proj + (long)b * Tc * U + u;
    const _Float16* pr = pz + (long)Mc * U;
    const _Float16* ph = pr + (long)Mc * U;
    float* po = out + ((long)b * T + t0) * U + u;

    _Float16 fz[PF], fr[PF], fh[PF];
    #pragma unroll
    for (int i = 0; i < PF; ++i) {
        const long o = (long)((i < Tc) ? i : (Tc - 1)) * U;
        fz[i] = pz[o]; fr[i] = pr[o]; fh[i] = ph[o];
    }

    for (int t = 0; t < Tc; t += PF) {
        #pragma unroll
        for (int i = 0; i < PF; ++i) {
            const float xz = (float)fz[i];
            const float xr = (float)fr[i];
            const float xh = (float)fh[i];
            {
                int tn = t + i + PF; if (tn > Tc - 1) tn = Tc - 1;
                const long o = (long)tn * U;
                fz[i] = pz[o]; fr[i] = pr[o]; fh[i] = ph[o];
            }
            const float e2r = __expf(2.f * (xr + h * vmr));
            const float rr  = 2.f - 2.f / (e2r + 1.f);             // tanh(.)+1
            const float zz  = 1.f / (1.f + __expf(-(xz + h * vmz)));
            const float e2h = __expf(2.f * (xh + rr * h));
            const float hh  = 1.f - 2.f / (e2h + 1.f);             // tanh(.)
            h = (1.f - zz) * hh + zz * h;
            if (t + i < Tc) po[(long)(t + i) * U] = h;
        }
    }
    hstate[idx] = h;
}

// ---------- launch ----------
extern "C" void kernel_launch(void* const* d_in, const int* in_sizes, int n_in,
                              void* d_out, int out_size, void* d_ws, size_t ws_size,
                              hipStream_t stream)
{
    const float* x  = (const float*)d_in[0];
    const float* wz = (const float*)d_in[1];
    const float* wr = (const float*)d_in[2];
    const float* wh = (const float*)d_in[3];
    const float* mz = (const float*)d_in[4];
    const float* mr = (const float*)d_in[5];
    const float* bz = (const float*)d_in[6];
    const float* br = (const float*)d_in[7];
    const float* bh = (const float*)d_in[8];

    const int B = 64, T = 512, D = 1024, U = 1024;

    const size_t h_bytes = (size_t)B * U * sizeof(float);
    const size_t w_bytes = (size_t)48 * WSLICE_STRIDE;   // 6.49 MB

    int Tc = T;
    while (Tc > 4) {
        const int Mc_ = B * Tc;
        const size_t a_bytes_ = (size_t)33 * 8 * Mc_ * 16;
        const size_t p_bytes_ = 3ull * Mc_ * U * sizeof(_Float16);
        if (h_bytes + w_bytes + a_bytes_ + p_bytes_ <= ws_size) break;
        Tc >>= 1;
    }
    const int nmt = B * Tc / 256;
    const int Mc  = B * Tc;
    const size_t a_bytes = (size_t)33 * 8 * Mc * 16;

    float*    h_state = (float*)d_ws;
    char*     Wblob   = (char*)d_ws + h_bytes;
    char*     Ablob   = (char*)d_ws + h_bytes + w_bytes;
    _Float16* proj    = (_Float16*)((char*)d_ws + h_bytes + w_bytes + a_bytes);

    bru_conv_w<<<48 * 8192 / 256, 256, 0, stream>>>(wz, wr, wh, Wblob, D, U);

    for (int t0 = 0; t0 < T; t0 += Tc) {
        bru_conv_a<<<(Mc * 32) / 256, 256, 0, stream>>>(x, Ablob, T, D, Tc, t0, Mc);

        bru_gemm_mfma<<<3 * nmt * 4, 512, 0, stream>>>(
            Ablob, Wblob, bz, br, bh, proj, nmt, U, Mc);

        bru_scan<<<(B * U) / 256, 256, 0, stream>>>(
            proj, mz, mr, (float*)d_out, h_state, B, T, U, Tc, t0, Mc);
    }
}

// Round 11
// 630.026 us; speedup vs baseline: 1.3161x; 1.3161x over previous
//
#include <hip/hip_runtime.h>
#include <cmath>

using f16x8  = __attribute__((ext_vector_type(8))) _Float16;
using f32x16 = __attribute__((ext_vector_type(16))) float;

// ---------- helpers ----------
__device__ __forceinline__ void gld16(void* lds, const void* g) {
    __builtin_amdgcn_global_load_lds(
        (const __attribute__((address_space(1))) unsigned int*)g,
        (__attribute__((address_space(3))) unsigned int*)lds, 16, 0, 0);
}

// ========= Layouts =========
// K_eff = 2048: k_eff = 2k + s, s=0 -> f16-hi(x), s=1 -> f16-lo residual.
// W_eff[2k+s][u] = w[k][u] (duplicated) so a SINGLE f16 MFMA chain computes
// hi*w + lo*w — same numerics as round 9's 2-product, standard GEMM structure.
//
// A-blob: per (mt, kt) 32KB: 256 m-rows x 128B (64 k_eff = 32 real k).
//   Row r, stored 16B slot sh holds k_eff octet qe = sh ^ (r&7)   [pre-swizzle]
//   octet content j=0..7: k_eff = kt*64 + qe*8 + j -> real k = kt*32+qe*4+(j>>1),
//   value = (j&1) ? lo : hi.  kt stride per mt padded to 33 (distance-1 stage).
// W-blob: per (nt12, kt) 32KB: 256 u-rows x 128B, same swizzle; octet content
//   j -> (f16)w[kt*32 + qe*4 + (j>>1)][u]  (each w duplicated).  Stride 33.
// Linear global_load_lds reproduces the swizzled image; ds_read_b128 at
// slot (kstep*2+lhi)^(row&7) is low-conflict (verified r2/r9 pattern).

// ---------- convert x -> A blob ----------
__global__ __launch_bounds__(256)
void bru_conv_a(const float* __restrict__ x, char* __restrict__ Ablob,
                int T, int D, int Tc, int t0, int Mc)
{
    const int gid = blockIdx.x * 256 + threadIdx.x;   // Mc*32 threads
    const int kt = gid / Mc;
    const int m  = gid - kt * Mc;
    const int mt = m >> 8, row = m & 255;

    const long xrow = (long)(m / Tc) * T + t0 + (m % Tc);
    const float* src = x + xrow * (long)D + kt * 32;

    float v[32];
    #pragma unroll
    for (int i = 0; i < 8; ++i)
        *(float4*)&v[i * 4] = *(const float4*)(src + i * 4);

    _Float16 hi[32], lo[32];
    #pragma unroll
    for (int k = 0; k < 32; ++k) {
        hi[k] = (_Float16)v[k];
        lo[k] = (_Float16)(v[k] - (float)hi[k]);
    }

    char* base = Ablob + ((size_t)(mt * 33 + kt)) * 32768 + (size_t)row * 128;
    #pragma unroll
    for (int qe = 0; qe < 8; ++qe) {
        _Float16 o[8];
        #pragma unroll
        for (int j = 0; j < 8; ++j) {
            const int k = qe * 4 + (j >> 1);
            o[j] = (j & 1) ? lo[k] : hi[k];
        }
        *(f16x8*)(base + ((qe ^ (row & 7)) << 4)) = *(f16x8*)o;
    }
}

// ---------- convert W (3 gates) -> W_eff blobs (duplicated along K) ----------
__global__ __launch_bounds__(256)
void bru_conv_w(const float* __restrict__ wz, const float* __restrict__ wr,
                const float* __restrict__ wh, char* __restrict__ Wblob,
                int D, int U)
{
    const int gid  = blockIdx.x * 256 + threadIdx.x;  // 12*32*2048 threads
    const int blob = gid >> 11;
    const int idx  = gid & 2047;
    const int qe   = idx >> 8;            // 0..7
    const int row  = idx & 255;           // consecutive -> coalesced u

    const int nt12 = blob >> 5;
    const int kt   = blob & 31;
    const int g    = nt12 >> 2;
    const int ntl  = nt12 & 3;

    const float* W = (g == 0) ? wz : (g == 1) ? wr : wh;
    const int ucol = ntl * 256 + row;

    _Float16 wf[4];
    #pragma unroll
    for (int jj = 0; jj < 4; ++jj)
        wf[jj] = (_Float16)W[(long)(kt * 32 + qe * 4 + jj) * U + ucol];

    _Float16 o[8];
    #pragma unroll
    for (int j = 0; j < 8; ++j) o[j] = wf[j >> 1];

    *(f16x8*)(Wblob + ((size_t)(nt12 * 33 + kt)) * 32768 + (size_t)row * 128
              + ((qe ^ (row & 7)) << 4)) = *(f16x8*)o;
}

// ---------- f16 MFMA GEMM over K_eff=2048 ----------
// Block 256x256; 8 waves 2x4, wave tile 128m x 64n, 32x32x16_f16.
// Both operands staged to LDS (2 x 64KB double buffer) via gld16 from
// pre-swizzled blobs; stage(kt+1) issued before compute(kt); one
// __syncthreads() per K-tile (its vmcnt(0) drains ~1500-cyc-old loads).
__global__ __launch_bounds__(512, 2)
void bru_gemm_mfma(const char* __restrict__ Ablob, const char* __restrict__ Wblob,
                   const float* __restrict__ bz, const float* __restrict__ br,
                   const float* __restrict__ bh,
                   _Float16* __restrict__ proj,
                   int nmt, int U, int Mc)
{
    __shared__ char sm[131072];   // [2 buf][A 32KB | B 32KB]

    const int ngrid = gridDim.x;
    const int bid   = blockIdx.x;
    int lid = bid;
    if ((ngrid & 7) == 0) lid = (bid & 7) * (ngrid >> 3) + (bid >> 3);
    const int mt   = lid / 12;
    const int nt12 = lid - mt * 12;
    const int g    = nt12 >> 2;
    const int ntl  = nt12 & 3;

    const int tid  = threadIdx.x;
    const int lane = tid & 63;
    const int w    = tid >> 6;
    const int wm   = w >> 2, wn = w & 3;   // 2x4 wave grid; wave tile 128x64
    const int l31  = lane & 31;
    const int lhi  = lane >> 5;
    const int r7   = l31 & 7;

    const char* asrc = Ablob + (size_t)(mt * 33) * 32768;
    const char* bsrc = Wblob + (size_t)(nt12 * 33) * 32768;

    // per-thread LDS byte bases (row&7 == r7 for all frags since i*32%8==0)
    const int abase = (wm * 128 + l31) * 128;            // + i*32*128
    const int bbase = 32768 + (wn * 64 + l31) * 128;     // + j*32*128

    f32x16 acc[4][2];
    #pragma unroll
    for (int i = 0; i < 4; ++i)
        #pragma unroll
        for (int j = 0; j < 2; ++j) acc[i][j] = (f32x16)0.f;

    // prologue: stage kt=0 into buf0
    #pragma unroll
    for (int c = 0; c < 4; ++c) {
        gld16(sm + c * 8192 + tid * 16,         asrc + c * 8192 + tid * 16);
        gld16(sm + 32768 + c * 8192 + tid * 16, bsrc + c * 8192 + tid * 16);
    }
    __syncthreads();   // vmcnt(0) + barrier

    for (int kt = 0; kt < 32; ++kt) {
        const int cur = (kt & 1) << 16;
        char* nxt = sm + (cur ^ 65536);
        const char* an = asrc + (size_t)(kt + 1) * 32768;
        const char* bn = bsrc + (size_t)(kt + 1) * 32768;

        // stage kt+1 (kt=31 stages the pad tile; drained but never read)
        #pragma unroll
        for (int c = 0; c < 4; ++c) {
            gld16(nxt + c * 8192 + tid * 16,         an + c * 8192 + tid * 16);
            gld16(nxt + 32768 + c * 8192 + tid * 16, bn + c * 8192 + tid * 16);
        }

        const char* smc = sm + cur;
        #pragma unroll
        for (int ks = 0; ks < 4; ++ks) {
            const int slot = ((ks * 2 + lhi) ^ r7) << 4;
            f16x8 af[4], bf[2];
            #pragma unroll
            for (int i = 0; i < 4; ++i)
                af[i] = *(const f16x8*)(smc + abase + i * 4096 + slot);
            #pragma unroll
            for (int j = 0; j < 2; ++j)
                bf[j] = *(const f16x8*)(smc + bbase + j * 4096 + slot);
            #pragma unroll
            for (int i = 0; i < 4; ++i)
                #pragma unroll
                for (int j = 0; j < 2; ++j)
                    acc[i][j] = __builtin_amdgcn_mfma_f32_32x32x16_f16(
                        af[i], bf[j], acc[i][j], 0, 0, 0);
        }

        __syncthreads();   // drains the early-issued stage; swaps buffers
    }

    // epilogue: C map (verified): col=lane&31, row=(reg&3)+8*(reg>>2)+4*(lane>>5)
    const float* bias = (g == 0) ? bz : (g == 1) ? br : bh;
    const int n0 = ntl * 256 + wn * 64;
    float bcol[2];
    #pragma unroll
    for (int j = 0; j < 2; ++j) bcol[j] = bias[n0 + j * 32 + l31];

    _Float16* cbase = proj + (size_t)g * Mc * U + (size_t)n0 + l31;
    #pragma unroll
    for (int i = 0; i < 4; ++i) {
        #pragma unroll
        for (int j = 0; j < 2; ++j) {
            #pragma unroll
            for (int reg = 0; reg < 16; ++reg) {
                const int row = mt * 256 + wm * 128 + i * 32
                              + (reg & 3) + 8 * (reg >> 2) + 4 * lhi;
                cbase[(size_t)row * U + j * 32] = (_Float16)(acc[i][j][reg] + bcol[j]);
            }
        }
    }
}

// ---------- scan: one thread per (b,u); 8-deep rotating register prefetch ----------
#define PF 8
__global__ __launch_bounds__(256)
void bru_scan(const _Float16* __restrict__ proj,
              const float* __restrict__ mz, const float* __restrict__ mr,
              float* __restrict__ out,
              float* __restrict__ hstate,
              int B, int T, int U, int Tc, int t0, int Mc)
{
    const int idx = blockIdx.x * blockDim.x + threadIdx.x;
    const int b = idx / U;
    const int u = idx - b * U;

    float h = (t0 == 0) ? 0.f : hstate[idx];
    const float vmz = mz[u];
    const float vmr = mr[u];

    const _Float16* pz = proj + (long)b * Tc * U + u;
    const _Float16* pr = pz + (long)Mc * U;
    const _Float16* ph = pr + (long)Mc * U;
    float* po = out + ((long)b * T + t0) * U + u;

    _Float16 fz[PF], fr[PF], fh[PF];
    #pragma unroll
    for (int i = 0; i < PF; ++i) {
        const long o = (long)((i < Tc) ? i : (Tc - 1)) * U;
        fz[i] = pz[o]; fr[i] = pr[o]; fh[i] = ph[o];
    }

    for (int t = 0; t < Tc; t += PF) {
        #pragma unroll
        for (int i = 0; i < PF; ++i) {
            const float xz = (float)fz[i];
            const float xr = (float)fr[i];
            const float xh = (float)fh[i];
            {
                int tn = t + i + PF; if (tn > Tc - 1) tn = Tc - 1;
                const long o = (long)tn * U;
                fz[i] = pz[o]; fr[i] = pr[o]; fh[i] = ph[o];
            }
            const float e2r = __expf(2.f * (xr + h * vmr));
            const float rr  = 2.f - 2.f / (e2r + 1.f);             // tanh(.)+1
            const float zz  = 1.f / (1.f + __expf(-(xz + h * vmz)));
            const float e2h = __expf(2.f * (xh + rr * h));
            const float hh  = 1.f - 2.f / (e2h + 1.f);             // tanh(.)
            h = (1.f - zz) * hh + zz * h;
            if (t + i < Tc) po[(long)(t + i) * U] = h;
        }
    }
    hstate[idx] = h;
}

// ---------- launch ----------
extern "C" void kernel_launch(void* const* d_in, const int* in_sizes, int n_in,
                              void* d_out, int out_size, void* d_ws, size_t ws_size,
                              hipStream_t stream)
{
    const float* x  = (const float*)d_in[0];
    const float* wz = (const float*)d_in[1];
    const float* wr = (const float*)d_in[2];
    const float* wh = (const float*)d_in[3];
    const float* mz = (const float*)d_in[4];
    const float* mr = (const float*)d_in[5];
    const float* bz = (const float*)d_in[6];
    const float* br = (const float*)d_in[7];
    const float* bh = (const float*)d_in[8];

    const int B = 64, T = 512, D = 1024, U = 1024;

    const size_t h_bytes = (size_t)B * U * sizeof(float);
    const size_t w_bytes = (size_t)12 * 33 * 32768;   // 12.98 MB incl. pad

    int Tc = T;
    while (Tc > 4) {
        const int nmt_ = B * Tc / 256;
        const size_t a_bytes_ = (size_t)nmt_ * 33 * 32768;
        const size_t p_bytes_ = 3ull * B * Tc * U * sizeof(_Float16);
        if (h_bytes + w_bytes + a_bytes_ + p_bytes_ <= ws_size) break;
        Tc >>= 1;
    }
    const int nmt = B * Tc / 256;
    const int Mc  = B * Tc;
    const size_t a_bytes = (size_t)nmt * 33 * 32768;

    float*    h_state = (float*)d_ws;
    char*     Wblob   = (char*)d_ws + h_bytes;
    char*     Ablob   = (char*)d_ws + h_bytes + w_bytes;
    _Float16* proj    = (_Float16*)((char*)d_ws + h_bytes + w_bytes + a_bytes);

    bru_conv_w<<<12 * 32 * 2048 / 256, 256, 0, stream>>>(wz, wr, wh, Wblob, D, U);

    for (int t0 = 0; t0 < T; t0 += Tc) {
        bru_conv_a<<<(Mc * 32) / 256, 256, 0, stream>>>(x, Ablob, T, D, Tc, t0, Mc);

        bru_gemm_mfma<<<3 * nmt * 4, 512, 0, stream>>>(
            Ablob, Wblob, bz, br, bh, proj, nmt, U, Mc);

        bru_scan<<<(B * U) / 256, 256, 0, stream>>>(
            proj, mz, mr, (float*)d_out, h_state, B, T, U, Tc, t0, Mc);
    }
}